// Round 10
// baseline (126.143 us; speedup 1.0000x reference)
//
#include <hip/hip_runtime.h>
#include <hip/hip_fp16.h>

// out[b][f] = sum_{k: rows[k]=f} vals[k] * inputs[b][cols[k]] + bias[f]
//
// R10: (a) inT stored as fp16; accumulate via scalar a += v*(float)h so
//      clang emits v_fma_mix_f32 (1 VALU/output, no unpack; also 8x better
//      gather precision than bf16). (b) col-QUARTER phase split (key =
//      (col>>10)*4096+row): per-phase working set 1MB/XCD so adjacent
//      phases co-fit in L2 despite inter-block drift.
// Structure else as R9: FT=16, BT=512, 8 waves, 2 feat/wave, bf16 LDS
// transpose tile, nt f32 stores, fused transpose||hist, 5 launches.

#define NF 4096
#define IND 4096
#define BATCH_TOTAL 4096
#define FT 16
#define BT 512
#define NT_MAIN 512
#define NPHASE 4
#define NKEYS (NPHASE * NF)                        // 16384
#define NTILES ((IND / 64) * (BATCH_TOTAL / 64))   // 4096 transpose tiles

typedef float f32x4 __attribute__((ext_vector_type(4)));

__device__ __forceinline__ float bf2f(unsigned short u) {
    return __uint_as_float(((unsigned int)u) << 16);
}
__device__ __forceinline__ unsigned short f2bf(float x) {
    unsigned int h = __float_as_uint(x);
    h += 0x7fff + ((h >> 16) & 1);   // round-to-nearest-even
    return (unsigned short)(h >> 16);
}

// ---------- F1: fused transpose->fp16 (blocks 0..NTILES-1) + quarter-hist ----------
__global__ __launch_bounds__(256)
void fused_transpose_hist(const float* __restrict__ in,
                          __half* __restrict__ outT,
                          const int* __restrict__ rows,
                          const int* __restrict__ cols,
                          int* __restrict__ cntq, int nnz) {
    if (blockIdx.x < NTILES) {
        __shared__ float t[64][65];
        const int tb = blockIdx.x;
        const int d0 = (tb & 63) * 64;
        const int b0 = (tb >> 6) * 64;
        const int tx4 = threadIdx.x & 15;
        const int ty  = threadIdx.x >> 4;
#pragma unroll
        for (int p = 0; p < 4; ++p) {
            int brow = ty + p * 16;
            float4 v = *(const float4*)(in + (long)(b0 + brow) * IND + d0 + tx4 * 4);
            t[brow][tx4 * 4 + 0] = v.x;
            t[brow][tx4 * 4 + 1] = v.y;
            t[brow][tx4 * 4 + 2] = v.z;
            t[brow][tx4 * 4 + 3] = v.w;
        }
        __syncthreads();
        const int bx4 = threadIdx.x & 15;
        const int dy  = threadIdx.x >> 4;
#pragma unroll
        for (int p = 0; p < 4; ++p) {
            int drow = dy + p * 16;
            __half h4[4];
            h4[0] = __float2half(t[bx4 * 4 + 0][drow]);
            h4[1] = __float2half(t[bx4 * 4 + 1][drow]);
            h4[2] = __float2half(t[bx4 * 4 + 2][drow]);
            h4[3] = __float2half(t[bx4 * 4 + 3][drow]);
            *(ushort4*)(outT + (long)(d0 + drow) * BATCH_TOTAL + b0 + bx4 * 4) =
                *(const ushort4*)h4;
        }
    } else {
        int k = (blockIdx.x - NTILES) * 256 + threadIdx.x;
        if (k < nnz) {
            int key = ((cols[k] >> 10) << 12) | rows[k];   // quarter*4096 + row
            atomicAdd(&cntq[key], 1);
        }
    }
}

// ---------- S1: exclusive scan of 16384 counts -> rptrq and cursorq ----------
__global__ __launch_bounds__(512)
void scan16k_kernel(const int* __restrict__ cntq, int* __restrict__ rptrq,
                    int* __restrict__ cursorq) {
    __shared__ int ts[512];
    const int t = threadIdx.x;
    const int base = t * 32;
    int e[32];
    int tot = 0;
#pragma unroll
    for (int i = 0; i < 32; ++i) { e[i] = cntq[base + i]; tot += e[i]; }
    ts[t] = tot;
    __syncthreads();
    for (int off = 1; off < 512; off <<= 1) {
        int v = (t >= off) ? ts[t - off] : 0;
        __syncthreads();
        ts[t] += v;
        __syncthreads();
    }
    int run = (t == 0) ? 0 : ts[t - 1];
#pragma unroll
    for (int i = 0; i < 32; ++i) {
        rptrq[base + i] = run;
        cursorq[base + i] = run;
        run += e[i];
    }
}

// ---------- S2: scatter entries sorted by (quarter, row) ----------
__global__ void scatter_pairsq_kernel(const float* __restrict__ vals,
                                      const int* __restrict__ rows,
                                      const int* __restrict__ cols,
                                      int* __restrict__ cursorq,
                                      int2* __restrict__ pairs, int nnz) {
    int k = blockIdx.x * blockDim.x + threadIdx.x;
    if (k < nnz) {
        int c = cols[k];
        int key = ((c >> 10) << 12) | rows[k];
        int p = atomicAdd(&cursorq[key], 1);
        pairs[p] = make_int2(c, __float_as_int(vals[k]));
    }
}

// ---------- per-segment AXPY walk (fp16 gather, fma_mix) ----------
__device__ __forceinline__ void walk_seg(const int2* __restrict__ pairs,
                                         int start, int n,
                                         const __half* __restrict__ gbase,
                                         float* __restrict__ a) {
#pragma unroll 4
    for (int k = 0; k < n; ++k) {
        int2 e = pairs[start + k];                       // uniform scalar
        float v = __int_as_float(e.y);
        union { uint4 u; __half h[8]; } U;
        U.u = *(const uint4*)(gbase + (long)e.x * BATCH_TOTAL);
#pragma unroll
        for (int j = 0; j < 8; ++j)
            a[j] += v * __half2float(U.h[j]);            // v_fma_mix_f32
    }
}

// ---------- K4: main CSR-AXPY (quarter-phased, dual-feature per wave) ----------
__global__ __launch_bounds__(NT_MAIN, 8)
void spmm_axpy_kernel(const __half* __restrict__ inT,
                      const int2* __restrict__ pairs,
                      const int* __restrict__ rptrq,
                      const int* __restrict__ cntq,
                      const float* __restrict__ bias,
                      float* __restrict__ out) {
#pragma clang fp contract(fast)
    __shared__ unsigned short tile[FT][BT + 8];  // 16.6 KB -> 4 blocks/CU

    // XCD-chunked bijective swizzle (nwg = 2048). fblk fastest within a
    // chunk: each XCD's resident blocks sweep fblks of ONE bt-slice, and
    // (via the h-loop) roughly the same col-quarter at the same time.
    const int bid = blockIdx.x;
    const int per = gridDim.x >> 3;            // 256
    const int wg = (bid & 7) * per + (bid >> 3);
    const int fblk = wg & (NF / FT - 1);       // 0..255
    const int bt   = wg >> 8;                  // 0..7
    const int b0 = bt * BT;
    const int fbase = fblk * FT;

    const int tid = threadIdx.x;
    const int wid = tid >> 6;                  // 0..7
    const int lane = tid & 63;

    const int fA = fbase + wid;                // features fbase+0..7
    const int fB = fbase + 8 + wid;            // features fbase+8..15

    float aA[8] = {0.f, 0.f, 0.f, 0.f, 0.f, 0.f, 0.f, 0.f};
    float aB[8] = {0.f, 0.f, 0.f, 0.f, 0.f, 0.f, 0.f, 0.f};
    const __half* gbase = inT + b0 + lane * 8;

#pragma unroll
    for (int h = 0; h < NPHASE; ++h) {         // col-quarter phases (outer!)
        const int oA = h * NF + fA;
        const int sA = __builtin_amdgcn_readfirstlane(rptrq[oA]);
        const int nA = __builtin_amdgcn_readfirstlane(cntq[oA]);
        walk_seg(pairs, sA, nA, gbase, aA);
        const int oB = h * NF + fB;
        const int sB = __builtin_amdgcn_readfirstlane(rptrq[oB]);
        const int nB = __builtin_amdgcn_readfirstlane(cntq[oB]);
        walk_seg(pairs, sB, nB, gbase, aB);
    }

    ushort4 p0, p1;
    p0.x = f2bf(aA[0]); p0.y = f2bf(aA[1]); p0.z = f2bf(aA[2]); p0.w = f2bf(aA[3]);
    p1.x = f2bf(aA[4]); p1.y = f2bf(aA[5]); p1.z = f2bf(aA[6]); p1.w = f2bf(aA[7]);
    *(ushort4*)(&tile[wid][lane * 8])     = p0;
    *(ushort4*)(&tile[wid][lane * 8 + 4]) = p1;
    p0.x = f2bf(aB[0]); p0.y = f2bf(aB[1]); p0.z = f2bf(aB[2]); p0.w = f2bf(aB[3]);
    p1.x = f2bf(aB[4]); p1.y = f2bf(aB[5]); p1.z = f2bf(aB[6]); p1.w = f2bf(aB[7]);
    *(ushort4*)(&tile[wid + 8][lane * 8])     = p0;
    *(ushort4*)(&tile[wid + 8][lane * 8 + 4]) = p1;
    __syncthreads();

    // Epilogue: out[b0+r][fbase..fbase+15] = tile[.][r] + bias, coalesced nt.
    const int chunk = tid & 3;                 // 4 f32x4 across 16 f
    const int rbase = tid >> 2;                // 128 rows of b per iter
    float4 bv = ((const float4*)bias)[(fbase >> 2) + chunk];
#pragma unroll
    for (int p = 0; p < 4; ++p) {
        int r = rbase + p * 128;
        f32x4 o;
        o.x = bf2f(tile[chunk * 4 + 0][r]) + bv.x;
        o.y = bf2f(tile[chunk * 4 + 1][r]) + bv.y;
        o.z = bf2f(tile[chunk * 4 + 2][r]) + bv.z;
        o.w = bf2f(tile[chunk * 4 + 3][r]) + bv.w;
        __builtin_nontemporal_store(
            o, (f32x4*)(out + (long)(b0 + r) * NF + fbase + chunk * 4));
    }
}

// ---------- Fallback (R2 structure) if ws too small ----------
__global__ void init_out_kernel(float* __restrict__ out,
                                const float* __restrict__ bias) {
    const int nf4 = NF / 4;
    const long total = (long)BATCH_TOTAL * nf4;
    const float4* b4 = (const float4*)bias;
    float4* o4 = (float4*)out;
    for (long i = (long)blockIdx.x * blockDim.x + threadIdx.x; i < total;
         i += (long)gridDim.x * blockDim.x)
        o4[i] = b4[i & (nf4 - 1)];
}

__global__ void hist_kernel(const int* __restrict__ rows,
                            int* __restrict__ cnt, int nnz) {
    int k = blockIdx.x * blockDim.x + threadIdx.x;
    if (k < nnz) atomicAdd(&cnt[rows[k]], 1);
}

__global__ __launch_bounds__(1024)
void scan_kernel(const int* __restrict__ cnt, int* __restrict__ rptr,
                 int* __restrict__ cursor) {
    __shared__ int ts[1024];
    const int t = threadIdx.x;
    const int base = t * 4;
    int e0 = cnt[base], e1 = cnt[base + 1], e2 = cnt[base + 2], e3 = cnt[base + 3];
    ts[t] = e0 + e1 + e2 + e3;
    __syncthreads();
    for (int off = 1; off < 1024; off <<= 1) {
        int v = (t >= off) ? ts[t - off] : 0;
        __syncthreads();
        ts[t] += v;
        __syncthreads();
    }
    int excl = (t == 0) ? 0 : ts[t - 1];
    int p0 = excl, p1 = excl + e0, p2 = p1 + e1, p3 = p2 + e2;
    rptr[base + 0] = p0;   cursor[base + 0] = p0;
    rptr[base + 1] = p1;   cursor[base + 1] = p1;
    rptr[base + 2] = p2;   cursor[base + 2] = p2;
    rptr[base + 3] = p3;   cursor[base + 3] = p3;
}

__global__ void scatter3_kernel(const float* __restrict__ vals,
                                const int* __restrict__ rows,
                                const int* __restrict__ cols,
                                int* __restrict__ cursor,
                                float* __restrict__ sval,
                                int* __restrict__ scol,
                                int* __restrict__ srow, int nnz) {
    int k = blockIdx.x * blockDim.x + threadIdx.x;
    if (k < nnz) {
        int r = rows[k];
        int p = atomicAdd(&cursor[r], 1);
        sval[p] = vals[k];
        scol[p] = cols[k];
        srow[p] = r;
    }
}

#define TILE_B_FB 4
__global__ __launch_bounds__(512, 4)
void spmm_csr_fb_kernel(const float* __restrict__ inputs,
                        const float* __restrict__ sval,
                        const int* __restrict__ scol,
                        const int* __restrict__ srow,
                        float* __restrict__ out, int nnz) {
    __shared__ float in_lds[TILE_B_FB][IND];
    const int tid = threadIdx.x;
    const long b0 = (long)blockIdx.x * TILE_B_FB;
    for (int i = tid; i < IND / 4; i += 512) {
#pragma unroll
        for (int j = 0; j < TILE_B_FB; ++j)
            ((float4*)in_lds[j])[i] = ((const float4*)(inputs + (b0 + j) * IND))[i];
    }
    __syncthreads();
    const int C = (nnz + 511) / 512;
    int k0 = tid * C, k1 = min(k0 + C, nnz);
    if (k0 < k1) {
        int cur = srow[k0];
        float a0 = 0.f, a1 = 0.f, a2 = 0.f, a3 = 0.f;
        for (int k = k0; k < k1; ++k) {
            int r = srow[k];
            float v = sval[k];
            int c = scol[k];
            if (r != cur) {
                atomicAdd(&out[(b0 + 0) * NF + cur], a0);
                atomicAdd(&out[(b0 + 1) * NF + cur], a1);
                atomicAdd(&out[(b0 + 2) * NF + cur], a2);
                atomicAdd(&out[(b0 + 3) * NF + cur], a3);
                a0 = a1 = a2 = a3 = 0.f;
                cur = r;
            }
            a0 += v * in_lds[0][c];
            a1 += v * in_lds[1][c];
            a2 += v * in_lds[2][c];
            a3 += v * in_lds[3][c];
        }
        atomicAdd(&out[(b0 + 0) * NF + cur], a0);
        atomicAdd(&out[(b0 + 1) * NF + cur], a1);
        atomicAdd(&out[(b0 + 2) * NF + cur], a2);
        atomicAdd(&out[(b0 + 3) * NF + cur], a3);
    }
}

extern "C" void kernel_launch(void* const* d_in, const int* in_sizes, int n_in,
                              void* d_out, int out_size, void* d_ws, size_t ws_size,
                              hipStream_t stream) {
    const float* inputs = (const float*)d_in[0];
    const float* vals   = (const float*)d_in[1];
    const int*   rows   = (const int*)d_in[2];
    const int*   cols   = (const int*)d_in[3];
    const float* bias   = (const float*)d_in[4];
    float* out = (float*)d_out;
    const int nnz = in_sizes[1];

    char* ws = (char*)d_ws;
    size_t off = 0;
    int* cntq    = (int*)(ws + off); off += (size_t)NKEYS * 4;   // 64 KB
    int* cursorq = (int*)(ws + off); off += (size_t)NKEYS * 4;   // 64 KB
    int* rptrq   = (int*)(ws + off); off += (size_t)NKEYS * 4;   // 64 KB
    size_t pairs_off = (off + 15) & ~(size_t)15;
    int2* pairs = (int2*)(ws + pairs_off);
    size_t after_pairs = (pairs_off + (size_t)nnz * 8 + 15) & ~(size_t)15;
    __half* inT = (__half*)(ws + after_pairs);
    size_t need_main = after_pairs + (size_t)IND * BATCH_TOTAL * 2;

    const int eb = (nnz + 255) / 256;

    if (need_main <= ws_size) {
        (void)hipMemsetAsync(cntq, 0, (size_t)NKEYS * 4, stream);
        fused_transpose_hist<<<NTILES + eb, 256, 0, stream>>>(
            inputs, inT, rows, cols, cntq, nnz);
        scan16k_kernel<<<1, 512, 0, stream>>>(cntq, rptrq, cursorq);
        scatter_pairsq_kernel<<<eb, 256, 0, stream>>>(vals, rows, cols, cursorq,
                                                      pairs, nnz);
        spmm_axpy_kernel<<<(NF / FT) * (BATCH_TOTAL / BT), NT_MAIN, 0, stream>>>(
            inT, pairs, rptrq, cntq, bias, out);
    } else {
        // Fallback: R2 structure (needs ~2.1 MB of ws).
        int* cnt    = cntq;
        int* cursor = cursorq;
        int* rptr   = rptrq;
        int*   srow = (int*)(ws + pairs_off);
        int*   scol = srow + nnz;
        float* sval = (float*)(scol + nnz);
        (void)hipMemsetAsync(cnt, 0, (size_t)NF * 4, stream);
        init_out_kernel<<<2048, 256, 0, stream>>>(out, bias);
        hist_kernel<<<eb, 256, 0, stream>>>(rows, cnt, nnz);
        scan_kernel<<<1, 1024, 0, stream>>>(cnt, rptr, cursor);
        scatter3_kernel<<<eb, 256, 0, stream>>>(vals, rows, cols, cursor,
                                                sval, scol, srow, nnz);
        spmm_csr_fb_kernel<<<BATCH_TOTAL / TILE_B_FB, 512, 0, stream>>>(
            inputs, sval, scol, srow, out, nnz);
    }
}

// Round 11
// 120.861 us; speedup vs baseline: 1.0437x; 1.0437x over previous
//
#include <hip/hip_runtime.h>
#include <hip/hip_fp16.h>

// out[b][f] = sum_{k: rows[k]=f} vals[k] * inputs[b][cols[k]] + bias[f]
//
// R11: R10 (quarter-phased, fp16 inT, fma_mix) + segment-transition fixes:
//  - seg descriptors packed {start,count} int2 -> 1 s_load each,
//  - ALL 8 descriptors prefetched at block top (independent scalar loads),
//  - dual-stream walk: fA & fB segments of a phase fused in one loop
//    (min-part unconditional + remainders) -> 2 independent load chains.
// Structure: FT=16, BT=512, 8 waves, bf16 LDS transpose tile, nt stores,
// fused transpose||hist, scan16k, scatter, main. 5 launches.

#define NF 4096
#define IND 4096
#define BATCH_TOTAL 4096
#define FT 16
#define BT 512
#define NT_MAIN 512
#define NPHASE 4
#define NKEYS (NPHASE * NF)                        // 16384
#define NTILES ((IND / 64) * (BATCH_TOTAL / 64))   // 4096 transpose tiles

typedef float f32x4 __attribute__((ext_vector_type(4)));

__device__ __forceinline__ float bf2f(unsigned short u) {
    return __uint_as_float(((unsigned int)u) << 16);
}
__device__ __forceinline__ unsigned short f2bf(float x) {
    unsigned int h = __float_as_uint(x);
    h += 0x7fff + ((h >> 16) & 1);   // round-to-nearest-even
    return (unsigned short)(h >> 16);
}

// ---------- F1: fused transpose->fp16 (blocks 0..NTILES-1) + quarter-hist ----------
__global__ __launch_bounds__(256)
void fused_transpose_hist(const float* __restrict__ in,
                          __half* __restrict__ outT,
                          const int* __restrict__ rows,
                          const int* __restrict__ cols,
                          int* __restrict__ cntq, int nnz) {
    if (blockIdx.x < NTILES) {
        __shared__ float t[64][65];
        const int tb = blockIdx.x;
        const int d0 = (tb & 63) * 64;
        const int b0 = (tb >> 6) * 64;
        const int tx4 = threadIdx.x & 15;
        const int ty  = threadIdx.x >> 4;
#pragma unroll
        for (int p = 0; p < 4; ++p) {
            int brow = ty + p * 16;
            float4 v = *(const float4*)(in + (long)(b0 + brow) * IND + d0 + tx4 * 4);
            t[brow][tx4 * 4 + 0] = v.x;
            t[brow][tx4 * 4 + 1] = v.y;
            t[brow][tx4 * 4 + 2] = v.z;
            t[brow][tx4 * 4 + 3] = v.w;
        }
        __syncthreads();
        const int bx4 = threadIdx.x & 15;
        const int dy  = threadIdx.x >> 4;
#pragma unroll
        for (int p = 0; p < 4; ++p) {
            int drow = dy + p * 16;
            __half h4[4];
            h4[0] = __float2half(t[bx4 * 4 + 0][drow]);
            h4[1] = __float2half(t[bx4 * 4 + 1][drow]);
            h4[2] = __float2half(t[bx4 * 4 + 2][drow]);
            h4[3] = __float2half(t[bx4 * 4 + 3][drow]);
            *(ushort4*)(outT + (long)(d0 + drow) * BATCH_TOTAL + b0 + bx4 * 4) =
                *(const ushort4*)h4;
        }
    } else {
        int k = (blockIdx.x - NTILES) * 256 + threadIdx.x;
        if (k < nnz) {
            int key = ((cols[k] >> 10) << 12) | rows[k];   // quarter*4096 + row
            atomicAdd(&cntq[key], 1);
        }
    }
}

// ---------- S1: scan 16384 counts -> seg {start,count} and cursorq ----------
__global__ __launch_bounds__(512)
void scan16k_kernel(const int* __restrict__ cntq, int2* __restrict__ seg,
                    int* __restrict__ cursorq) {
    __shared__ int ts[512];
    const int t = threadIdx.x;
    const int base = t * 32;
    int e[32];
    int tot = 0;
#pragma unroll
    for (int i = 0; i < 32; ++i) { e[i] = cntq[base + i]; tot += e[i]; }
    ts[t] = tot;
    __syncthreads();
    for (int off = 1; off < 512; off <<= 1) {
        int v = (t >= off) ? ts[t - off] : 0;
        __syncthreads();
        ts[t] += v;
        __syncthreads();
    }
    int run = (t == 0) ? 0 : ts[t - 1];
#pragma unroll
    for (int i = 0; i < 32; ++i) {
        seg[base + i] = make_int2(run, e[i]);
        cursorq[base + i] = run;
        run += e[i];
    }
}

// ---------- S2: scatter entries sorted by (quarter, row) ----------
__global__ void scatter_pairsq_kernel(const float* __restrict__ vals,
                                      const int* __restrict__ rows,
                                      const int* __restrict__ cols,
                                      int* __restrict__ cursorq,
                                      int2* __restrict__ pairs, int nnz) {
    int k = blockIdx.x * blockDim.x + threadIdx.x;
    if (k < nnz) {
        int c = cols[k];
        int key = ((c >> 10) << 12) | rows[k];
        int p = atomicAdd(&cursorq[key], 1);
        pairs[p] = make_int2(c, __float_as_int(vals[k]));
    }
}

// ---------- single-entry update ----------
__device__ __forceinline__ void upd(const int2 e,
                                    const __half* __restrict__ gbase,
                                    float* __restrict__ a) {
    float v = __int_as_float(e.y);
    union { uint4 u; __half h[8]; } U;
    U.u = *(const uint4*)(gbase + (long)e.x * BATCH_TOTAL);
#pragma unroll
    for (int j = 0; j < 8; ++j)
        a[j] += v * __half2float(U.h[j]);            // v_fma_mix_f32
}

// ---------- K4: main CSR-AXPY (quarter-phased, dual-stream per wave) ----------
__global__ __launch_bounds__(NT_MAIN, 8)
void spmm_axpy_kernel(const __half* __restrict__ inT,
                      const int2* __restrict__ pairs,
                      const int2* __restrict__ seg,
                      const float* __restrict__ bias,
                      float* __restrict__ out) {
#pragma clang fp contract(fast)
    __shared__ unsigned short tile[FT][BT + 8];  // 16.6 KB -> 4 blocks/CU

    // XCD-chunked bijective swizzle (nwg = 2048); fblk fastest within chunk.
    const int bid = blockIdx.x;
    const int per = gridDim.x >> 3;            // 256
    const int wg = (bid & 7) * per + (bid >> 3);
    const int fblk = wg & (NF / FT - 1);       // 0..255
    const int bt   = wg >> 8;                  // 0..7
    const int b0 = bt * BT;
    const int fbase = fblk * FT;

    const int tid = threadIdx.x;
    const int wid = tid >> 6;                  // 0..7
    const int lane = tid & 63;

    const int fA = fbase + wid;                // features fbase+0..7
    const int fB = fbase + 8 + wid;            // features fbase+8..15

    // Prefetch ALL segment descriptors up front (8 independent s_loads).
    int sA[NPHASE], nA[NPHASE], sB[NPHASE], nB[NPHASE];
#pragma unroll
    for (int h = 0; h < NPHASE; ++h) {
        int2 dA = seg[h * NF + fA];
        int2 dB = seg[h * NF + fB];
        sA[h] = __builtin_amdgcn_readfirstlane(dA.x);
        nA[h] = __builtin_amdgcn_readfirstlane(dA.y);
        sB[h] = __builtin_amdgcn_readfirstlane(dB.x);
        nB[h] = __builtin_amdgcn_readfirstlane(dB.y);
    }

    float aA[8] = {0.f, 0.f, 0.f, 0.f, 0.f, 0.f, 0.f, 0.f};
    float aB[8] = {0.f, 0.f, 0.f, 0.f, 0.f, 0.f, 0.f, 0.f};
    const __half* gbase = inT + b0 + lane * 8;

#pragma unroll
    for (int h = 0; h < NPHASE; ++h) {         // col-quarter phases (outer)
        const int m = min(nA[h], nB[h]);
        // fused dual-stream part: two independent chains per iteration
#pragma unroll 2
        for (int k = 0; k < m; ++k) {
            int2 eA = pairs[sA[h] + k];
            int2 eB = pairs[sB[h] + k];
            upd(eA, gbase, aA);
            upd(eB, gbase, aB);
        }
        // remainders (uniform trip counts)
        for (int k = m; k < nA[h]; ++k) upd(pairs[sA[h] + k], gbase, aA);
        for (int k = m; k < nB[h]; ++k) upd(pairs[sB[h] + k], gbase, aB);
    }

    ushort4 p0, p1;
    p0.x = f2bf(aA[0]); p0.y = f2bf(aA[1]); p0.z = f2bf(aA[2]); p0.w = f2bf(aA[3]);
    p1.x = f2bf(aA[4]); p1.y = f2bf(aA[5]); p1.z = f2bf(aA[6]); p1.w = f2bf(aA[7]);
    *(ushort4*)(&tile[wid][lane * 8])     = p0;
    *(ushort4*)(&tile[wid][lane * 8 + 4]) = p1;
    p0.x = f2bf(aB[0]); p0.y = f2bf(aB[1]); p0.z = f2bf(aB[2]); p0.w = f2bf(aB[3]);
    p1.x = f2bf(aB[4]); p1.y = f2bf(aB[5]); p1.z = f2bf(aB[6]); p1.w = f2bf(aB[7]);
    *(ushort4*)(&tile[wid + 8][lane * 8])     = p0;
    *(ushort4*)(&tile[wid + 8][lane * 8 + 4]) = p1;
    __syncthreads();

    // Epilogue: out[b0+r][fbase..fbase+15] = tile[.][r] + bias, coalesced nt.
    const int chunk = tid & 3;                 // 4 f32x4 across 16 f
    const int rbase = tid >> 2;                // 128 rows of b per iter
    float4 bv = ((const float4*)bias)[(fbase >> 2) + chunk];
#pragma unroll
    for (int p = 0; p < 4; ++p) {
        int r = rbase + p * 128;
        f32x4 o;
        o.x = bf2f(tile[chunk * 4 + 0][r]) + bv.x;
        o.y = bf2f(tile[chunk * 4 + 1][r]) + bv.y;
        o.z = bf2f(tile[chunk * 4 + 2][r]) + bv.z;
        o.w = bf2f(tile[chunk * 4 + 3][r]) + bv.w;
        __builtin_nontemporal_store(
            o, (f32x4*)(out + (long)(b0 + r) * NF + fbase + chunk * 4));
    }
}

// ---------- Fallback (R2 structure) if ws too small ----------
__global__ void init_out_kernel(float* __restrict__ out,
                                const float* __restrict__ bias) {
    const int nf4 = NF / 4;
    const long total = (long)BATCH_TOTAL * nf4;
    const float4* b4 = (const float4*)bias;
    float4* o4 = (float4*)out;
    for (long i = (long)blockIdx.x * blockDim.x + threadIdx.x; i < total;
         i += (long)gridDim.x * blockDim.x)
        o4[i] = b4[i & (nf4 - 1)];
}

__global__ void hist_kernel(const int* __restrict__ rows,
                            int* __restrict__ cnt, int nnz) {
    int k = blockIdx.x * blockDim.x + threadIdx.x;
    if (k < nnz) atomicAdd(&cnt[rows[k]], 1);
}

__global__ __launch_bounds__(1024)
void scan_kernel(const int* __restrict__ cnt, int* __restrict__ rptr,
                 int* __restrict__ cursor) {
    __shared__ int ts[1024];
    const int t = threadIdx.x;
    const int base = t * 4;
    int e0 = cnt[base], e1 = cnt[base + 1], e2 = cnt[base + 2], e3 = cnt[base + 3];
    ts[t] = e0 + e1 + e2 + e3;
    __syncthreads();
    for (int off = 1; off < 1024; off <<= 1) {
        int v = (t >= off) ? ts[t - off] : 0;
        __syncthreads();
        ts[t] += v;
        __syncthreads();
    }
    int excl = (t == 0) ? 0 : ts[t - 1];
    int p0 = excl, p1 = excl + e0, p2 = p1 + e1, p3 = p2 + e2;
    rptr[base + 0] = p0;   cursor[base + 0] = p0;
    rptr[base + 1] = p1;   cursor[base + 1] = p1;
    rptr[base + 2] = p2;   cursor[base + 2] = p2;
    rptr[base + 3] = p3;   cursor[base + 3] = p3;
}

__global__ void scatter3_kernel(const float* __restrict__ vals,
                                const int* __restrict__ rows,
                                const int* __restrict__ cols,
                                int* __restrict__ cursor,
                                float* __restrict__ sval,
                                int* __restrict__ scol,
                                int* __restrict__ srow, int nnz) {
    int k = blockIdx.x * blockDim.x + threadIdx.x;
    if (k < nnz) {
        int r = rows[k];
        int p = atomicAdd(&cursor[r], 1);
        sval[p] = vals[k];
        scol[p] = cols[k];
        srow[p] = r;
    }
}

#define TILE_B_FB 4
__global__ __launch_bounds__(512, 4)
void spmm_csr_fb_kernel(const float* __restrict__ inputs,
                        const float* __restrict__ sval,
                        const int* __restrict__ scol,
                        const int* __restrict__ srow,
                        float* __restrict__ out, int nnz) {
    __shared__ float in_lds[TILE_B_FB][IND];
    const int tid = threadIdx.x;
    const long b0 = (long)blockIdx.x * TILE_B_FB;
    for (int i = tid; i < IND / 4; i += 512) {
#pragma unroll
        for (int j = 0; j < TILE_B_FB; ++j)
            ((float4*)in_lds[j])[i] = ((const float4*)(inputs + (b0 + j) * IND))[i];
    }
    __syncthreads();
    const int C = (nnz + 511) / 512;
    int k0 = tid * C, k1 = min(k0 + C, nnz);
    if (k0 < k1) {
        int cur = srow[k0];
        float a0 = 0.f, a1 = 0.f, a2 = 0.f, a3 = 0.f;
        for (int k = k0; k < k1; ++k) {
            int r = srow[k];
            float v = sval[k];
            int c = scol[k];
            if (r != cur) {
                atomicAdd(&out[(b0 + 0) * NF + cur], a0);
                atomicAdd(&out[(b0 + 1) * NF + cur], a1);
                atomicAdd(&out[(b0 + 2) * NF + cur], a2);
                atomicAdd(&out[(b0 + 3) * NF + cur], a3);
                a0 = a1 = a2 = a3 = 0.f;
                cur = r;
            }
            a0 += v * in_lds[0][c];
            a1 += v * in_lds[1][c];
            a2 += v * in_lds[2][c];
            a3 += v * in_lds[3][c];
        }
        atomicAdd(&out[(b0 + 0) * NF + cur], a0);
        atomicAdd(&out[(b0 + 1) * NF + cur], a1);
        atomicAdd(&out[(b0 + 2) * NF + cur], a2);
        atomicAdd(&out[(b0 + 3) * NF + cur], a3);
    }
}

extern "C" void kernel_launch(void* const* d_in, const int* in_sizes, int n_in,
                              void* d_out, int out_size, void* d_ws, size_t ws_size,
                              hipStream_t stream) {
    const float* inputs = (const float*)d_in[0];
    const float* vals   = (const float*)d_in[1];
    const int*   rows   = (const int*)d_in[2];
    const int*   cols   = (const int*)d_in[3];
    const float* bias   = (const float*)d_in[4];
    float* out = (float*)d_out;
    const int nnz = in_sizes[1];

    char* ws = (char*)d_ws;
    size_t off = 0;
    int*  cntq    = (int*)(ws + off);  off += (size_t)NKEYS * 4;   // 64 KB
    int*  cursorq = (int*)(ws + off);  off += (size_t)NKEYS * 4;   // 64 KB
    int2* seg     = (int2*)(ws + off); off += (size_t)NKEYS * 8;   // 128 KB
    size_t pairs_off = (off + 15) & ~(size_t)15;
    int2* pairs = (int2*)(ws + pairs_off);
    size_t after_pairs = (pairs_off + (size_t)nnz * 8 + 15) & ~(size_t)15;
    __half* inT = (__half*)(ws + after_pairs);
    size_t need_main = after_pairs + (size_t)IND * BATCH_TOTAL * 2;

    const int eb = (nnz + 255) / 256;

    if (need_main <= ws_size) {
        (void)hipMemsetAsync(cntq, 0, (size_t)NKEYS * 4, stream);
        fused_transpose_hist<<<NTILES + eb, 256, 0, stream>>>(
            inputs, inT, rows, cols, cntq, nnz);
        scan16k_kernel<<<1, 512, 0, stream>>>(cntq, seg, cursorq);
        scatter_pairsq_kernel<<<eb, 256, 0, stream>>>(vals, rows, cols, cursorq,
                                                      pairs, nnz);
        spmm_axpy_kernel<<<(NF / FT) * (BATCH_TOTAL / BT), NT_MAIN, 0, stream>>>(
            inT, pairs, seg, bias, out);
    } else {
        // Fallback: R2 structure (needs ~2.1 MB of ws).
        int* cnt    = cntq;
        int* cursor = cursorq;
        int* rptr   = (int*)seg;
        int*   srow = (int*)(ws + pairs_off);
        int*   scol = srow + nnz;
        float* sval = (float*)(scol + nnz);
        (void)hipMemsetAsync(cnt, 0, (size_t)NF * 4, stream);
        init_out_kernel<<<2048, 256, 0, stream>>>(out, bias);
        hist_kernel<<<eb, 256, 0, stream>>>(rows, cnt, nnz);
        scan_kernel<<<1, 1024, 0, stream>>>(cnt, rptr, cursor);
        scatter3_kernel<<<eb, 256, 0, stream>>>(vals, rows, cols, cursor,
                                                sval, scol, srow, nnz);
        spmm_csr_fb_kernel<<<BATCH_TOTAL / TILE_B_FB, 512, 0, stream>>>(
            inputs, sval, scol, srow, out, nnz);
    }
}